// Round 1
// baseline (2234.982 us; speedup 1.0000x reference)
//
#include <hip/hip_runtime.h>

// VQ layer: z (16,64,64,64) f32, emb (4096,64) f32.
// Token t=(b,h,w): argmax_k ( z_t . e_k - 0.5*||e_k||^2 )  ==  argmin_k ||z_t - e_k||^2
// out[b][c][h][w] = emb[best][c]
//
// Layout facts:
//   z[b][c][h][w] flat = b*262144 + c*4096 + hw   (feature stride 4096 floats)
//   consecutive threads = consecutive hw -> all per-c global accesses coalesced.

#define C_ 64
#define HW_ 4096
#define K_ 4096
#define CHUNK_ 64   // codes staged in LDS per iteration (64*64*4 = 16 KB)

__global__ __launch_bounds__(256) void vq_fp32_kernel(
    const float* __restrict__ z, const float* __restrict__ emb,
    float* __restrict__ out)
{
    __shared__ float se[CHUNK_ * C_];   // code chunk, row-major [code][c]
    __shared__ float snorm[CHUNK_];     // 0.5*||e||^2 per staged code

    const int t  = blockIdx.x * 256 + threadIdx.x;   // token id, 0..65535
    const int b  = t >> 12;                          // / (H*W)
    const int hw = t & (HW_ - 1);

    // Load this token's 64 features into registers (coalesced across lanes).
    const float* zt = z + (size_t)b * (C_ * HW_) + hw;
    float zf[C_];
#pragma unroll
    for (int c = 0; c < C_; ++c) zf[c] = zt[(size_t)c * HW_];

    float best    = -3.4e38f;
    int   bestIdx = 0;

    for (int k0 = 0; k0 < K_; k0 += CHUNK_) {
        __syncthreads();   // previous chunk fully consumed
        // Stage CHUNK_ codes: 4096 floats = 1024 float4, 256 threads x 4.
        const float4* src = (const float4*)(emb + (size_t)k0 * C_);
        float4*       dst = (float4*)se;
#pragma unroll
        for (int i = 0; i < (CHUNK_ * C_ / 4) / 256; ++i)
            dst[i * 256 + threadIdx.x] = src[i * 256 + threadIdx.x];
        __syncthreads();

        // Half-norms for the staged chunk (threads 0..63, one code each).
        if (threadIdx.x < CHUNK_) {
            float s = 0.f;
#pragma unroll
            for (int c = 0; c < C_; ++c) {
                float v = se[threadIdx.x * C_ + c];
                s = fmaf(v, v, s);
            }
            snorm[threadIdx.x] = 0.5f * s;
        }
        __syncthreads();

        // Score every staged code; LDS reads are wave-broadcast (same addr
        // for all 64 lanes -> no bank conflicts).
#pragma unroll 4
        for (int kk = 0; kk < CHUNK_; ++kk) {
            float dot = 0.f;
#pragma unroll
            for (int c = 0; c < C_; ++c)
                dot = fmaf(zf[c], se[kk * C_ + c], dot);
            float score = dot - snorm[kk];
            if (score > best) { best = score; bestIdx = k0 + kk; }
        }
    }

    // Gather winning code, scatter to NCHW (coalesced across lanes per c).
    const float* e  = emb + (size_t)bestIdx * C_;
    float*       ot = out + (size_t)b * (C_ * HW_) + hw;
#pragma unroll
    for (int c = 0; c < C_; ++c) ot[(size_t)c * HW_] = e[c];
}

extern "C" void kernel_launch(void* const* d_in, const int* in_sizes, int n_in,
                              void* d_out, int out_size, void* d_ws, size_t ws_size,
                              hipStream_t stream) {
    const float* z   = (const float*)d_in[0];   // (16,64,64,64)
    const float* emb = (const float*)d_in[1];   // (4096,64)
    float*       out = (float*)d_out;           // (16,64,64,64)

    // 65536 tokens, 1 per thread.
    vq_fp32_kernel<<<256, 256, 0, stream>>>(z, emb, out);
}

// Round 5
// 220.440 us; speedup vs baseline: 10.1387x; 10.1387x over previous
//
#include <hip/hip_runtime.h>

// VQ layer, fp32-accurate MFMA path (bf16x3 split-precision emulation).
// score(t,k) = z_t.e_k - 0.5||e_k||^2 ; argmax_k == argmin_k ||z_t-e_k||^2.
// x = h1+h2+h3 (bf16 each, residual ~2^-27 rel). Products kept:
//   h1g1 (1), h1g2+h2g1 (2^-9), h2g2+h1g3+h3g1 (2^-18); dropped <=2^-27.
// Accumulate from C=0 smallest-first (partials <= ~8 -> rounding ~5e-7),
// subtract 0.5||e||^2 once in fp32 epilogue => total score noise ~2.5e-6,
// same class as the Round-1 pure-fp32 kernel that matched np with absmax 0.
//
// d_ws: [0, 1.5MB)           emb B-fragments, 3-level bf16, frag-linear
//       [1.5MB, 1.5MB+16KB)  0.5*||e||^2 fp32 per code
// Fallback to pure-fp32 kernel if ws_size too small.

typedef __attribute__((ext_vector_type(8))) short short8;
typedef __attribute__((ext_vector_type(4))) float f32x4;
typedef unsigned int u32;
typedef __attribute__((address_space(3))) u32 lds_u32;
typedef const __attribute__((address_space(1))) u32 glb_u32;

#define NCHUNK 256                        // 4096 codes / 16 per chunk
#define GROUP 4                           // chunks staged per barrier
#define NGROUP 64
#define FRAGS 6                           // 3 levels x 2 K-halves
#define CHUNK_BYTES (FRAGS * 64 * 16)     // 6144
#define GROUP_BYTES (GROUP * CHUNK_BYTES) // 24576
#define WSB_BYTES (NCHUNK * CHUNK_BYTES)  // 1572864
#define WS_NEEDED ((size_t)WSB_BYTES + 16384u)

static __device__ __forceinline__ unsigned short f2bf(float f) {
    u32 u = __builtin_bit_cast(u32, f);
    u += 0x7fffu + ((u >> 16) & 1u);      // RNE; inputs finite Gaussians
    return (unsigned short)(u >> 16);
}
static __device__ __forceinline__ float bf2f(unsigned short h) {
    u32 u = ((u32)h) << 16;
    return __builtin_bit_cast(float, u);
}

// ---- prep 1: half-norms (exact fp32) -------------------------------------
__global__ void vq_norm_kernel(const float* __restrict__ emb, float* __restrict__ nrm) {
    int c = blockIdx.x * 256 + threadIdx.x;       // 4096 codes
    const float* e = emb + c * 64;
    float s = 0.f;
#pragma unroll
    for (int k = 0; k < 64; ++k) { float v = e[k]; s = fmaf(v, v, s); }
    nrm[c] = 0.5f * s;
}

// ---- prep 2: pack emb into 3-level bf16 B-fragments ----------------------
// 16B-group id = (ck*6 + f)*64 + lane;  f = level*2 + s (s = K-half).
// B-frag (16x16x32): n = lane&15, k = s*32 + (lane>>4)*8 + j.
// grid: 256 blocks (one per chunk) x 384 threads (6 frags x 64 lanes).
__global__ void vq_pack_kernel(const float* __restrict__ emb, unsigned short* __restrict__ wsB) {
    int ck    = blockIdx.x;
    int f     = threadIdx.x >> 6;
    int lane  = threadIdx.x & 63;
    int level = f >> 1, s = f & 1;
    int code  = ck * 16 + (lane & 15);
    int kb    = s * 32 + (lane >> 4) * 8;
    const float* src = emb + code * 64 + kb;
    short8 o;
#pragma unroll
    for (int j = 0; j < 8; ++j) {
        float x = src[j];
        unsigned short h1 = f2bf(x);
        float r1 = x - bf2f(h1);
        unsigned short h2 = f2bf(r1);
        float r2 = r1 - bf2f(h2);
        unsigned short h3 = f2bf(r2);
        o[j] = (short)(level == 0 ? h1 : (level == 1 ? h2 : h3));
    }
    ((short8*)wsB)[(ck * FRAGS + f) * 64 + lane] = o;
}

// ---- main: Round-3 structure (ran on HW), bf16x3 numerics ----------------
// 512 blocks x 256 threads (4 waves). Block owns 128 tokens; wave owns 32
// (2 A-tiles) and scores them against all 4096 codes.
__global__ __launch_bounds__(256, 2) void vq_main_kernel(
    const float* __restrict__ z, const float* __restrict__ emb,
    const unsigned short* __restrict__ wsB, const float* __restrict__ wsN,
    float* __restrict__ out)
{
    __shared__ char  sB[2][GROUP_BYTES];  // 2 x 24 KB double buffer
    __shared__ float sN[2][64];           // staged 0.5||e||^2 per group
    __shared__ int   sBest[128];

    const int wave = threadIdx.x >> 6;
    const int lane = threadIdx.x & 63;
    const int quad = lane >> 4;
    const int col  = lane & 15;

    const int t0 = blockIdx.x * 128 + wave * 32;

    // A fragments, 3-level split: a[tile][level][half], k = half*32+quad*8+j
    short8 a[2][3][2];
#pragma unroll
    for (int t = 0; t < 2; ++t) {
        const int tok = t0 + t * 16 + col;
        const int b   = tok >> 12;
        const int hw  = tok & 4095;
        const float* zp = z + b * 262144 + hw;
#pragma unroll
        for (int s = 0; s < 2; ++s)
#pragma unroll
            for (int j = 0; j < 8; ++j) {
                int k = s * 32 + quad * 8 + j;
                float x = zp[k * 4096];            // coalesced over col lanes
                unsigned short h1 = f2bf(x);
                float r1 = x - bf2f(h1);
                unsigned short h2 = f2bf(r1);
                float r2 = r1 - bf2f(h2);
                a[t][0][s][j] = (short)h1;
                a[t][1][s][j] = (short)h2;
                a[t][2][s][j] = (short)f2bf(r2);
            }
    }

    float best[2][4];
    int   bidx[2][4];
#pragma unroll
    for (int t = 0; t < 2; ++t)
#pragma unroll
        for (int r = 0; r < 4; ++r) { best[t][r] = -3.4e38f; bidx[t][r] = 0; }

    // async stage one 24 KB group: wave w copies chunk w (6 KB = six 1 KB
    // ops, dst = uniform base + lane*16). Wave 0 also stages the group's 64
    // norms (one 256 B op, dst = base + lane*4) — keeps vmcnt waits off the
    // critical path (no global loads inside the compute loop).
    auto stage = [&](int buf, int g) {
        const char* gbase = ((const char*)wsB) + g * GROUP_BYTES + wave * CHUNK_BYTES;
        char*       lbase = sB[buf] + wave * CHUNK_BYTES;
#pragma unroll
        for (int i = 0; i < 6; ++i)
            __builtin_amdgcn_global_load_lds(
                (glb_u32*)(gbase + i * 1024 + lane * 16),
                (lds_u32*)(lbase + i * 1024), 16, 0, 0);
        if (wave == 0)
            __builtin_amdgcn_global_load_lds(
                (glb_u32*)(wsN + g * 64 + lane),
                (lds_u32*)&sN[buf][0], 4, 0, 0);
    };

    stage(0, 0);

    for (int g = 0; g < NGROUP; ++g) {
        const int cur = g & 1;
        __syncthreads();                  // own vmcnt drained, all waves here
        if (g + 1 < NGROUP) stage(cur ^ 1, g + 1);

#pragma unroll
        for (int cl = 0; cl < GROUP; ++cl) {
            const int ck = g * GROUP + cl;
            const char* base = sB[cur] + cl * CHUNK_BYTES;
            // lane-contiguous b128 reads: conflict-free
            short8 b10 = ((const short8*)(base + 0 * 1024))[lane]; // h1, K-half0
            short8 b11 = ((const short8*)(base + 1 * 1024))[lane]; // h1, K-half1
            short8 b20 = ((const short8*)(base + 2 * 1024))[lane]; // h2
            short8 b21 = ((const short8*)(base + 3 * 1024))[lane];
            short8 b30 = ((const short8*)(base + 4 * 1024))[lane]; // h3
            short8 b31 = ((const short8*)(base + 5 * 1024))[lane];
            const float nrm  = sN[cur][cl * 16 + col];  // broadcast-class read
            const int   code = ck * 16 + col;  // C/D: col=lane&15, row=quad*4+r

#pragma unroll
            for (int t = 0; t < 2; ++t) {
                f32x4 acc = {0.f, 0.f, 0.f, 0.f};
                // smallest terms first (2^-18): h2g2, h1g3, h3g1
                acc = __builtin_amdgcn_mfma_f32_16x16x32_bf16(a[t][1][0], b20, acc, 0, 0, 0);
                acc = __builtin_amdgcn_mfma_f32_16x16x32_bf16(a[t][1][1], b21, acc, 0, 0, 0);
                acc = __builtin_amdgcn_mfma_f32_16x16x32_bf16(a[t][0][0], b30, acc, 0, 0, 0);
                acc = __builtin_amdgcn_mfma_f32_16x16x32_bf16(a[t][0][1], b31, acc, 0, 0, 0);
                acc = __builtin_amdgcn_mfma_f32_16x16x32_bf16(a[t][2][0], b10, acc, 0, 0, 0);
                acc = __builtin_amdgcn_mfma_f32_16x16x32_bf16(a[t][2][1], b11, acc, 0, 0, 0);
                // then 2^-9: h1g2, h2g1
                acc = __builtin_amdgcn_mfma_f32_16x16x32_bf16(a[t][0][0], b20, acc, 0, 0, 0);
                acc = __builtin_amdgcn_mfma_f32_16x16x32_bf16(a[t][0][1], b21, acc, 0, 0, 0);
                acc = __builtin_amdgcn_mfma_f32_16x16x32_bf16(a[t][1][0], b10, acc, 0, 0, 0);
                acc = __builtin_amdgcn_mfma_f32_16x16x32_bf16(a[t][1][1], b11, acc, 0, 0, 0);
                // main term h1g1 last
                acc = __builtin_amdgcn_mfma_f32_16x16x32_bf16(a[t][0][0], b10, acc, 0, 0, 0);
                acc = __builtin_amdgcn_mfma_f32_16x16x32_bf16(a[t][0][1], b11, acc, 0, 0, 0);

#pragma unroll
                for (int r = 0; r < 4; ++r) {
                    float score = acc[r] - nrm;   // single fp32 epilogue round
                    if (score > best[t][r]) { best[t][r] = score; bidx[t][r] = code; }
                }
            }
        }
    }

    // reduce across the 16 cols of each quad group; ties -> lowest index
#pragma unroll
    for (int off = 1; off < 16; off <<= 1)
#pragma unroll
        for (int t = 0; t < 2; ++t)
#pragma unroll
            for (int r = 0; r < 4; ++r) {
                float os = __shfl_xor(best[t][r], off, 64);
                int   oi = __shfl_xor(bidx[t][r], off, 64);
                if (os > best[t][r] || (os == best[t][r] && oi < bidx[t][r])) {
                    best[t][r] = os; bidx[t][r] = oi;
                }
            }
    if (col == 0)
#pragma unroll
        for (int t = 0; t < 2; ++t)
#pragma unroll
            for (int r = 0; r < 4; ++r)
                sBest[wave * 32 + t * 16 + quad * 4 + r] = bidx[t][r];
    __syncthreads();

    // output: 128 tokens x 64 c; lanes = consecutive tokens -> coalesced
    const int tk   = threadIdx.x & 127;
    const int coff = (threadIdx.x >> 7) * 32;
    const int gt   = blockIdx.x * 128 + tk;
    const int ob   = gt >> 12, ohw = gt & 4095;
    float* op = out + ob * 262144 + ohw;
    const float4* ep = (const float4*)(emb + sBest[tk] * 64 + coff);
#pragma unroll
    for (int i = 0; i < 8; ++i) {
        float4 v = ep[i];
        op[(coff + 4 * i + 0) * 4096] = v.x;
        op[(coff + 4 * i + 1) * 4096] = v.y;
        op[(coff + 4 * i + 2) * 4096] = v.z;
        op[(coff + 4 * i + 3) * 4096] = v.w;
    }
}

// ---- fallback (proven Round-1 kernel; used only if ws is too small) ------
__global__ __launch_bounds__(256) void vq_fp32_kernel(
    const float* __restrict__ z, const float* __restrict__ emb,
    float* __restrict__ out)
{
    __shared__ float se[64 * 64];
    __shared__ float snorm[64];

    const int t  = blockIdx.x * 256 + threadIdx.x;
    const int b  = t >> 12;
    const int hw = t & 4095;
    const float* zt = z + (size_t)b * 262144 + hw;
    float zf[64];
#pragma unroll
    for (int c = 0; c < 64; ++c) zf[c] = zt[(size_t)c * 4096];

    float best = -3.4e38f;
    int   bestIdx = 0;
    for (int k0 = 0; k0 < 4096; k0 += 64) {
        __syncthreads();
        const float4* src = (const float4*)(emb + (size_t)k0 * 64);
        float4*       dst = (float4*)se;
#pragma unroll
        for (int i = 0; i < 4; ++i)
            dst[i * 256 + threadIdx.x] = src[i * 256 + threadIdx.x];
        __syncthreads();
        if (threadIdx.x < 64) {
            float s = 0.f;
#pragma unroll
            for (int c = 0; c < 64; ++c) {
                float v = se[threadIdx.x * 64 + c];
                s = fmaf(v, v, s);
            }
            snorm[threadIdx.x] = 0.5f * s;
        }
        __syncthreads();
#pragma unroll 4
        for (int kk = 0; kk < 64; ++kk) {
            float dot = 0.f;
#pragma unroll
            for (int c = 0; c < 64; ++c)
                dot = fmaf(zf[c], se[kk * 64 + c], dot);
            float score = dot - snorm[kk];
            if (score > best) { best = score; bestIdx = k0 + kk; }
        }
    }
    const float* e  = emb + (size_t)bestIdx * 64;
    float*       ot = out + (size_t)b * 262144 + hw;
#pragma unroll
    for (int c = 0; c < 64; ++c) ot[(size_t)c * 4096] = e[c];
}

extern "C" void kernel_launch(void* const* d_in, const int* in_sizes, int n_in,
                              void* d_out, int out_size, void* d_ws, size_t ws_size,
                              hipStream_t stream) {
    const float* z   = (const float*)d_in[0];
    const float* emb = (const float*)d_in[1];
    float*       out = (float*)d_out;

    if (ws_size < WS_NEEDED) {          // constant per session: graph-safe
        vq_fp32_kernel<<<256, 256, 0, stream>>>(z, emb, out);
        return;
    }

    unsigned short* wsB = (unsigned short*)d_ws;                   // 1.5 MB
    float*          wsN = (float*)((char*)d_ws + WSB_BYTES);       // 16 KB

    vq_norm_kernel<<<16, 256, 0, stream>>>(emb, wsN);
    vq_pack_kernel<<<256, 384, 0, stream>>>(emb, wsB);
    vq_main_kernel<<<512, 256, 0, stream>>>(z, emb, wsB, wsN, out);
}